// Round 6
// baseline (153.524 us; speedup 1.0000x reference)
//
#include <hip/hip_runtime.h>
#include <hip/hip_bf16.h>

// HMM forward, chunk-parallel + MFMA. B=64, T=4096, S=64.
//
// R6 change vs R5: scale wave concurrency. R1-R5 established: per-wave
// step time ~700-770ns is INVARIANT to compute (R4), layout (R3), and
// write volume (R5); only wave count moved throughput (R1->R2: 2x waves
// -> 1.78x steps/us). Each wave sustains only ~48 cache-lines per ~860cy
// (per-wave memory-concurrency limit); chip fill rate proves 2.6x more
// line BW is available per CU. So: LL=16, C_CH=256 -> 1024 waves (4/CU,
// was 2/CU). Steps/wave 57->41 (1.44x total wave-steps, 2x concurrency).
// WARM=24 unchanged -> per-boundary accuracy identical (correction is
// exact; warm length only sets convergence).
//
// Linear-space recurrence (R4): v = 2^(alpha*log2e - 6s), Ahat=exp(T)*2^-6.
//   step: d[jt] = sum_kb mfma16(Ahat, pack_bf16(v)); v' = d * exp(emis)
//   drift |log2 v| small over 41 steps (fp32-safe); bf16 relative
//   precision is scale-free. phi = -150*ln2 for chunk 0 (exact t=0
//   anchor), 0 elsewhere (absorbed by phaseC correction).
// Data flow (R5): phaseA stores bf16(v) rows to a wave-private 32KB slab
// (sequential at DRAM, scatter L2-contained); phaseC scans boundary
// deltas, decodes alpha = log2(v)*ln2 + 6(r+25)*ln2 + phi + delta, and
// does WRITE-ONLY coalesced f32 stores of out + log_Z.

#define BB 64
#define TT 4096
#define SS 64
#define C_CH 256
#define LL 16
#define WARM 24
#define PF 8
#define WSLAB 16384          // ushorts per wave slab (16 tasks x 16 rows x 64)

typedef __attribute__((ext_vector_type(4))) short bh4;
typedef __attribute__((ext_vector_type(4))) float f32x4;
typedef __attribute__((ext_vector_type(4))) unsigned short us4;

#define LOG2E 1.44269504088896340736f
#define LN2F  0.69314718055994530942f

__device__ __forceinline__ float fexp2(float x) {
#if __has_builtin(__builtin_amdgcn_exp2f)
    return __builtin_amdgcn_exp2f(x);
#else
    return exp2f(x);
#endif
}
__device__ __forceinline__ float flog2(float x) {
#if __has_builtin(__builtin_amdgcn_logf)
    return __builtin_amdgcn_logf(x);
#else
    return log2f(x);
#endif
}
__device__ __forceinline__ int pack_bf16(float x, float y) {
    __hip_bfloat162 h = __float22bfloat162_rn(make_float2(x, y));
    int r; __builtin_memcpy(&r, &h, 4); return r;
}
__device__ __forceinline__ float bf_to_f32(unsigned short u) {
    unsigned int w = ((unsigned int)u) << 16;
    float f; __builtin_memcpy(&f, &w, 4); return f;
}
union PB2 { int i[2]; bh4 v; us4 u; };

__device__ __forceinline__ f32x4 mfma16(bh4 a, bh4 b, f32x4 c) {
#if __has_builtin(__builtin_amdgcn_mfma_f32_16x16x16bf16_1k)
    return __builtin_amdgcn_mfma_f32_16x16x16bf16_1k(a, b, c, 0, 0, 0);
#else
    asm("v_mfma_f32_16x16x16_bf16 %0, %1, %2, %0" : "+v"(c) : "v"(a), "v"(b));
    return c;
#endif
}

// One linear-space recurrence step for 16 tasks.
//   vv[kb] holds v[task=lane&15][j = 16*kb + 4q + r]  (B-layout == D-layout)
//   eE[jt] = exp(emis_row[j]) elementwise (2^-6 folded into Af).
__device__ __forceinline__ void do_step(f32x4 (&vv)[4], const f32x4 (&eE)[4],
                                        const bh4 (&Af)[4][4]) {
    bh4 Bf[4];
    #pragma unroll
    for (int kb = 0; kb < 4; ++kb) {
        PB2 pb;
        pb.i[0] = pack_bf16(vv[kb].x, vv[kb].y);
        pb.i[1] = pack_bf16(vv[kb].z, vv[kb].w);
        Bf[kb] = pb.v;
    }
    #pragma unroll
    for (int jt = 0; jt < 4; ++jt) {
        f32x4 d0 = {0.f, 0.f, 0.f, 0.f};
        f32x4 d1 = {0.f, 0.f, 0.f, 0.f};
        d0 = mfma16(Af[jt][0], Bf[0], d0);
        d1 = mfma16(Af[jt][1], Bf[1], d1);
        d0 = mfma16(Af[jt][2], Bf[2], d0);
        d1 = mfma16(Af[jt][3], Bf[3], d1);
        f32x4 d = d0 + d1;
        vv[jt] = d * eE[jt];
    }
}

__device__ __forceinline__ void load_row(f32x4 (&dst)[4],
                                         const float* __restrict__ eb,
                                         int t, int off) {
    const float* p = eb + (t & (TT - 1)) * SS + off;
    #pragma unroll
    for (int jt = 0; jt < 4; ++jt)
        dst[jt] = *(const f32x4*)(p + 16 * jt);
}

__global__ __launch_bounds__(64)
__attribute__((amdgpu_waves_per_eu(1, 1)))
void hmm_phaseA(const float* __restrict__ trans,
                const float* __restrict__ emis,
                unsigned short* __restrict__ wsv,
                float* __restrict__ ws_warm,
                float* __restrict__ ws_bound) {
    const int lane = threadIdx.x;
    const int n = lane & 15, q = lane >> 4;
    const int w = blockIdx.x;                  // 0..1023
    const int b = w >> 4, cg = w & 15;
    const int c = 16 * cg + n;                 // this lane's task (0..255)
    const bool is_c0 = (c == 0);
    const int off = 4 * q;

    // A-fragments (K=16): A_jt,kb[m=n][k=4q+e] = exp(T[16kb+4q+e][16jt+n])
    // with the constant per-step rescale 2^-6 folded in.
    bh4 Af[4][4];
    #pragma unroll
    for (int jt = 0; jt < 4; ++jt)
        #pragma unroll
        for (int kb = 0; kb < 4; ++kb) {
            float v0 = __expf(trans[(16 * kb + 4 * q + 0) * SS + 16 * jt + n]) * 0.015625f;
            float v1 = __expf(trans[(16 * kb + 4 * q + 1) * SS + 16 * jt + n]) * 0.015625f;
            float v2 = __expf(trans[(16 * kb + 4 * q + 2) * SS + 16 * jt + n]) * 0.015625f;
            float v3 = __expf(trans[(16 * kb + 4 * q + 3) * SS + 16 * jt + n]) * 0.015625f;
            PB2 pb;
            pb.i[0] = pack_bf16(v0, v1);
            pb.i[1] = pack_bf16(v2, v3);
            Af[jt][kb] = pb.v;
        }

    const float* eb = emis + (size_t)b * TT * SS;
    unsigned short* wslab = wsv + (size_t)w * WSLAB;

    const int t0 = LL * c - (WARM + 1);        // per-lane; c=0 => -25

    // phi = -150*ln2 for chunk 0 so its t=0 anchor is EXACT.
    const float cL = is_c0 ? (-150.0f * LN2F) : 0.0f;

    // Init: v = exp(emis[t0]) (pseudo; garbage-warm for c=0), plus the
    // true alpha0 row pre-exped for the c0 override.
    f32x4 vv[4], e0v[4], ebuf[PF][4];
    {
        f32x4 a0[4], z0[4];
        load_row(a0, eb, t0, off);
        load_row(z0, eb, 0, off);
        #pragma unroll
        for (int jt = 0; jt < 4; ++jt) {
            vv[jt].x = fexp2(a0[jt].x * LOG2E);
            vv[jt].y = fexp2(a0[jt].y * LOG2E);
            vv[jt].z = fexp2(a0[jt].z * LOG2E);
            vv[jt].w = fexp2(a0[jt].w * LOG2E);
            e0v[jt].x = fexp2(z0[jt].x * LOG2E);
            e0v[jt].y = fexp2(z0[jt].y * LOG2E);
            e0v[jt].z = fexp2(z0[jt].z * LOG2E);
            e0v[jt].w = fexp2(z0[jt].w * LOG2E);
        }
    }
    #pragma unroll
    for (int k = 0; k < PF; ++k) load_row(ebuf[k], eb, t0 + 1 + k, off);

    // Warm-up: s = 1..24 (3 groups of PF=8), no stores, no log path.
    #pragma unroll 1
    for (int g = 0; g < 3; ++g) {
        #pragma unroll
        for (int k = 0; k < PF; ++k) {
            int s = PF * g + k + 1;
            f32x4 eE[4];
            #pragma unroll
            for (int jt = 0; jt < 4; ++jt) {
                eE[jt].x = fexp2(ebuf[k][jt].x * LOG2E);
                eE[jt].y = fexp2(ebuf[k][jt].y * LOG2E);
                eE[jt].z = fexp2(ebuf[k][jt].z * LOG2E);
                eE[jt].w = fexp2(ebuf[k][jt].w * LOG2E);
            }
            load_row(ebuf[k], eb, t0 + s + PF, off);
            do_step(vv, eE, Af);
        }
    }
    // Boundary (uncorrected) alpha at t = 16c-1 (s=24): lane n holds j=0.
    if (lane < 16)
        ws_warm[b * C_CH + 16 * cg + lane] =
            fmaf(flog2(vv[0].x), LN2F, 144.0f * LN2F + cL);

    // Main: s = 25..40; store bf16(v) row (s-25) into the wave slab.
    // Slab layout: [task n][row r][j] ushort; lane (n,q) stores 4x us4
    // (8B each) at j = 16kb+4q. Scatter stays inside the wave's 32KB
    // window (L2-resident); slab stream sequential at DRAM.
    #pragma unroll 1
    for (int g = 0; g < 2; ++g) {
        #pragma unroll
        for (int k = 0; k < PF; ++k) {
            int s = WARM + 1 + PF * g + k;
            f32x4 eE[4];
            #pragma unroll
            for (int jt = 0; jt < 4; ++jt) {
                eE[jt].x = fexp2(ebuf[k][jt].x * LOG2E);
                eE[jt].y = fexp2(ebuf[k][jt].y * LOG2E);
                eE[jt].z = fexp2(ebuf[k][jt].z * LOG2E);
                eE[jt].w = fexp2(ebuf[k][jt].w * LOG2E);
            }
            load_row(ebuf[k], eb, t0 + s + PF, off);
            do_step(vv, eE, Af);
            if (k == 0 && g == 0 && is_c0) {
                // chunk 0: replace garbage warm result with true alpha0
                // (phi = -150*ln2 makes the decoded value exactly emis[0]).
                #pragma unroll
                for (int jt = 0; jt < 4; ++jt) vv[jt] = e0v[jt];
            }
            unsigned short* wp = wslab + (n * LL + (s - (WARM + 1))) * 64 + 4 * q;
            #pragma unroll
            for (int kb = 0; kb < 4; ++kb) {
                PB2 pb;
                pb.i[0] = pack_bf16(vv[kb].x, vv[kb].y);
                pb.i[1] = pack_bf16(vv[kb].z, vv[kb].w);
                *(us4*)(wp + 16 * kb) = pb.u;
            }
        }
    }
    if (lane < 16)
        ws_bound[b * C_CH + 16 * cg + lane] =
            fmaf(flog2(vv[0].x), LN2F, 240.0f * LN2F + cL);
}

// phaseC: per-chunk block (b,c). Redundant prefix-scan of boundary deltas,
// then read the chunk's bf16 v from the slab (2KB contiguous, L3-warm),
// decode alpha = log2(v)*ln2 + 6*(r+25)*ln2 + phi + delta, write 4KB
// contiguous f32 into out. Block (b, C-1) also emits log_Z.
__global__ __launch_bounds__(256)
void hmm_phaseC(float* __restrict__ out,
                const unsigned short* __restrict__ wsv,
                const float* __restrict__ ws_warm,
                const float* __restrict__ ws_bound) {
    const int b = blockIdx.x, c = blockIdx.y, tid = threadIdx.x;
    __shared__ float sd[C_CH];

    if (tid < C_CH) {
        float d = 0.f;
        if (tid > 0)
            d = ws_bound[b * C_CH + tid - 1] - ws_warm[b * C_CH + tid];
        sd[tid] = d;
    }
    __syncthreads();
    #pragma unroll
    for (int off = 1; off < C_CH; off <<= 1) {
        float v = 0.f;
        if (tid >= off && tid < C_CH) v = sd[tid - off];
        __syncthreads();
        if (tid >= off && tid < C_CH) sd[tid] += v;
        __syncthreads();
    }
    const float delta = sd[c];

    // This chunk's slab region: wave (b*16 + c>>4), task c&15.
    const int cg = c >> 4, n = c & 15;
    const unsigned short* src =
        wsv + (size_t)(b * 16 + cg) * WSLAB + n * (LL * 64) + tid * 4;
    const int r = tid >> 4, col0 = (tid & 15) * 4;

    us4 u0 = *(const us4*)(src);

    const float cs = fmaf(6.0f * (float)(r + 25), LN2F,
                          (c == 0 ? -150.0f * LN2F : 0.0f) + delta);
    float a[4];
    #pragma unroll
    for (int i = 0; i < 4; ++i)
        a[i] = fmaf(flog2(bf_to_f32(u0[i])), LN2F, cs);

    float* dst = out + (size_t)b * TT * SS + (size_t)(LL * c + r) * SS + col0;
    *(f32x4*)(dst) = *(f32x4*)&a[0];

    // log_Z from the corrected last row (r == 15 -> tid 240..255, in-wave).
    if (c == C_CH - 1 && tid >= 240) {
        float mx = fmaxf(fmaxf(a[0], a[1]), fmaxf(a[2], a[3]));
        #pragma unroll
        for (int off = 8; off >= 1; off >>= 1)
            mx = fmaxf(mx, __shfl_xor(mx, off, 64));
        float sv = __expf(a[0] - mx) + __expf(a[1] - mx)
                 + __expf(a[2] - mx) + __expf(a[3] - mx);
        #pragma unroll
        for (int off = 8; off >= 1; off >>= 1)
            sv += __shfl_xor(sv, off, 64);
        if (tid == 240)
            out[(size_t)BB * TT * SS + b] = mx + __logf(sv);
    }
}

extern "C" void kernel_launch(void* const* d_in, const int* in_sizes, int n_in,
                              void* d_out, int out_size, void* d_ws, size_t ws_size,
                              hipStream_t stream) {
    const float* trans = (const float*)d_in[0];   // (S,S)
    const float* emis  = (const float*)d_in[1];   // (B,T,S)
    // d_in[2] = seq_lens — unused by the reference.
    float* out = (float*)d_out;                   // alpha (B,T,S) ++ log_Z (B,)

    float* ws_warm  = (float*)d_ws;               // B*C floats
    float* ws_bound = ws_warm + BB * C_CH;        // B*C floats
    unsigned short* wsv =
        (unsigned short*)(ws_bound + BB * C_CH);  // 1024 * WSLAB ushorts

    hmm_phaseA<<<dim3(BB * 16), dim3(64), 0, stream>>>(trans, emis, wsv,
                                                       ws_warm, ws_bound);
    hmm_phaseC<<<dim3(BB, C_CH), dim3(256), 0, stream>>>(out, wsv,
                                                         ws_warm, ws_bound);
}